// Round 15
// baseline (9889.735 us; speedup 1.0000x reference)
//
#include <hip/hip_runtime.h>
#include <math.h>

// Problem constants
#define B_ 256
#define S_ 128
#define F_ 128
#define H_ 512
#define A_ 512
#define C_ 128
#define HSLICE (H_ * B_)

#define DOT4(va, vb) ((va).x*(vb).x + (va).y*(vb).y + (va).z*(vb).z + (va).w*(vb).w)

// ---------------------------------------------------------------------------
// sc1 helpers (tiny-traffic publishes only) + packed group barrier
// ---------------------------------------------------------------------------
__device__ __forceinline__ void stf(float* p, float v) {
    __hip_atomic_store(p, v, __ATOMIC_RELAXED, __HIP_MEMORY_SCOPE_AGENT);
}
__device__ __forceinline__ void sti(int* p, int v) {
    __hip_atomic_store(p, v, __ATOMIC_RELAXED, __HIP_MEMORY_SCOPE_AGENT);
}
__device__ __forceinline__ float ldf_sc(const float* p) {
    return __hip_atomic_load(p, __ATOMIC_RELAXED, __HIP_MEMORY_SCOPE_AGENT);
}

// wait for 128 packed flags [gbase, gbase+128) to reach target (8 lines polled)
__device__ __forceinline__ void group_wait128(const int* __restrict__ flags,
                                              int gbase, int tid, int target)
{
    if (tid < 64) {
        while (true) {
            int v0 = __hip_atomic_load(&flags[gbase + tid], __ATOMIC_RELAXED,
                                       __HIP_MEMORY_SCOPE_AGENT);
            int v1 = __hip_atomic_load(&flags[gbase + 64 + tid], __ATOMIC_RELAXED,
                                       __HIP_MEMORY_SCOPE_AGENT);
            int mn = v0 < v1 ? v0 : v1;
            if (__all(mn >= target)) break;
            __builtin_amdgcn_s_sleep(4);
        }
    }
}

// ---------------------------------------------------------------------------
// deep-prefetch k-major dot: 32-float double-buffer window.
// acc slots 0..3 = r0,r1,z0,z1 ; acc[NH],acc[NH+1] = n0,n1 partial.
// ---------------------------------------------------------------------------
template<int NH>
__device__ __forceinline__ void acc_chunks(const float* __restrict__ src,
                                           const float* __restrict__ W6k,
                                           int nk, int b, float* __restrict__ acc)
{
    float a0[32], a1[32];
#pragma unroll
    for (int j = 0; j < 32; ++j) a0[j] = src[(size_t)j * B_ + b];
    for (int kc = 0; kc < nk; kc += 32) {
        if (kc + 32 < nk) {
#pragma unroll
            for (int j = 0; j < 32; ++j)
                a1[j] = src[(size_t)(kc + 32 + j) * B_ + b];
        }
        const float* Wr = W6k + (size_t)kc * 6;
#pragma unroll
        for (int j = 0; j < 32; ++j) {
            float av = a0[j];
            acc[0]    = fmaf(av, Wr[j * 6 + 0], acc[0]);
            acc[1]    = fmaf(av, Wr[j * 6 + 1], acc[1]);
            acc[2]    = fmaf(av, Wr[j * 6 + 2], acc[2]);
            acc[3]    = fmaf(av, Wr[j * 6 + 3], acc[3]);
            acc[NH]   = fmaf(av, Wr[j * 6 + 4], acc[NH]);
            acc[NH+1] = fmaf(av, Wr[j * 6 + 5], acc[NH + 1]);
        }
#pragma unroll
        for (int j = 0; j < 32; ++j) a0[j] = a1[j];
    }
}

// per-lane x-row (128 contiguous floats) against W6 x-part; n -> slots 4,5
__device__ __forceinline__ void acc_xrow(const float4* __restrict__ xr,
                                         const float* __restrict__ W6k,
                                         float* __restrict__ acc)
{
    float4 c0[8], c1[8];
#pragma unroll
    for (int j = 0; j < 8; ++j) c0[j] = xr[j];
    for (int q = 0; q < 32; q += 8) {
        if (q + 8 < 32) {
#pragma unroll
            for (int j = 0; j < 8; ++j) c1[j] = xr[q + 8 + j];
        }
#pragma unroll
        for (int j = 0; j < 8; ++j) {
            const float* Wr = W6k + (size_t)((q + j) * 4) * 6;
            float e0 = c0[j].x, e1 = c0[j].y, e2 = c0[j].z, e3 = c0[j].w;
#pragma unroll
            for (int t2 = 0; t2 < 4; ++t2) {
                float av = (t2 == 0) ? e0 : (t2 == 1) ? e1 : (t2 == 2) ? e2 : e3;
                acc[0] = fmaf(av, Wr[t2 * 6 + 0], acc[0]);
                acc[1] = fmaf(av, Wr[t2 * 6 + 1], acc[1]);
                acc[2] = fmaf(av, Wr[t2 * 6 + 2], acc[2]);
                acc[3] = fmaf(av, Wr[t2 * 6 + 3], acc[3]);
                acc[4] = fmaf(av, Wr[t2 * 6 + 4], acc[4]);
                acc[5] = fmaf(av, Wr[t2 * 6 + 5], acc[5]);
            }
        }
#pragma unroll
        for (int j = 0; j < 8; ++j) c0[j] = c1[j];
    }
}

// GRU epilogue: combine partials, gate math, publish two h values (sc1)
__device__ __forceinline__ void gru_epilogue(const float* __restrict__ acc,
                                             const float accL[][6], int li,
                                             const float* __restrict__ bias4,
                                             int u0, int u1,
                                             float hold0, float hold1,
                                             float* __restrict__ houtT, int b)
{
    const float4 bb0 = *(const float4*)(bias4 + u0 * 4);
    const float4 bb1 = *(const float4*)(bias4 + u1 * 4);
    float rr0 = 1.f / (1.f + expf(-(acc[0] + accL[li][0] + bb0.x)));
    float rr1 = 1.f / (1.f + expf(-(acc[1] + accL[li][1] + bb1.x)));
    float zz0 = 1.f / (1.f + expf(-(acc[2] + accL[li][2] + bb0.y)));
    float zz1 = 1.f / (1.f + expf(-(acc[3] + accL[li][3] + bb1.y)));
    float hn0 = acc[6] + accL[li][4] + bb0.w;
    float hn1 = acc[7] + accL[li][5] + bb1.w;
    float nn0 = tanhf(acc[4] + bb0.z + rr0 * hn0);
    float nn1 = tanhf(acc[5] + bb1.z + rr1 * hn1);
    stf(&houtT[(size_t)u0 * B_ + b], (1.f - zz0) * nn0 + zz0 * hold0);
    stf(&houtT[(size_t)u1 * B_ + b], (1.f - zz1) * nn1 + zz1 * hold1);
}

// ---------------------------------------------------------------------------
// prep_all: W6e pack + xT transpose + biases + h0T zero + flags zero.
// ---------------------------------------------------------------------------
__global__ __launch_bounds__(256)
void prep_all(const float* __restrict__ x,
              const float* __restrict__ eWih, const float* __restrict__ eWhh,
              const float* __restrict__ ebih, const float* __restrict__ ebhh,
              const float* __restrict__ dbih, const float* __restrict__ dbhh,
              float* __restrict__ xT, float* __restrict__ W6e,
              float* __restrict__ bias4e, float* __restrict__ bias4d,
              float* __restrict__ h0T, int* __restrict__ dflags)
{
    int id = blockIdx.x * 256 + threadIdx.x;   // < 983040
    {
        int up = id / 3840;
        int rem = id - up * 3840;
        int k = rem / 6, g = rem - k * 6;
        int row = (g >> 1) * H_ + up * 2 + (g & 1);
        float val;
        if (k < F_) val = eWih[(size_t)row * F_ + k];
        else        val = eWhh[(size_t)row * H_ + (k - F_)];
        W6e[id] = val;
    }
#pragma unroll
    for (int r = 0; r < 5; ++r) {
        int xid = id + r * 983040;
        if (xid < S_ * F_ * B_) {
            int b2 = xid & 255, f = (xid >> 8) & 127, t = xid >> 15;
            xT[xid] = x[(size_t)b2 * (S_ * F_) + (size_t)t * F_ + f];
        }
    }
    if (id < H_ * B_) h0T[id] = 0.f;
    if (id < 512) dflags[id] = 0;
    if (id < H_) {
        bias4e[id * 4 + 0] = ebih[id] + ebhh[id];
        bias4e[id * 4 + 1] = ebih[H_ + id] + ebhh[H_ + id];
        bias4e[id * 4 + 2] = ebih[2 * H_ + id];
        bias4e[id * 4 + 3] = ebhh[2 * H_ + id];
        bias4d[id * 4 + 0] = dbih[id] + dbhh[id];
        bias4d[id * 4 + 1] = dbih[H_ + id] + dbhh[H_ + id];
        bias4d[id * 4 + 2] = dbih[2 * H_ + id];
        bias4d[id * 4 + 3] = dbhh[2 * H_ + id];
    }
}

// prep_dec: W6d pack only.
__global__ __launch_bounds__(256)
void prep_dec(const float* __restrict__ dWih, const float* __restrict__ dWhh,
              float* __restrict__ W6d)
{
    int id = blockIdx.x * 256 + threadIdx.x;
    int up = id / 3840;
    int rem = id - up * 3840;
    int k = rem / 6, g = rem - k * 6;
    int row = (g >> 1) * H_ + up * 2 + (g & 1);
    float val;
    if (k < F_) val = dWih[(size_t)row * F_ + k];
    else        val = dWhh[(size_t)row * H_ + (k - F_)];
    W6d[id] = val;
}

// ---------------------------------------------------------------------------
// Encoder GRU step (round-14, validated): grid 1024 = up(256) x bh(4), 128 thr.
// ---------------------------------------------------------------------------
__global__ __launch_bounds__(128)
void gru_step(const float* __restrict__ inT,
              const float* __restrict__ hinT,
              const float* __restrict__ W6,
              const float* __restrict__ bias4,
              float* __restrict__ houtT)
{
    __shared__ float accL[64][6];
    const int tid = threadIdx.x;
    const int lane = tid & 63;
    const int kw = tid >> 6;
    const int up = blockIdx.x & 255;
    const int bh = blockIdx.x >> 8;
    const int b = bh * 64 + lane;
    const float* Wb = W6 + (size_t)up * 3840;
    const int u0 = up * 2, u1 = u0 + 1;

    float acc[8];
#pragma unroll
    for (int g = 0; g < 8; ++g) acc[g] = 0.f;

    float hold0 = 0.f, hold1 = 0.f;
    if (kw == 0) {
        hold0 = hinT[(size_t)u0 * B_ + b];
        hold1 = hinT[(size_t)u1 * B_ + b];
        acc_chunks<4>(inT, Wb, F_, b, acc);
        acc_chunks<6>(hinT, Wb + F_ * 6, 192, b, acc);
    } else {
        acc_chunks<6>(hinT + (size_t)192 * B_, Wb + 320 * 6, 320, b, acc);
    }

    if (kw == 1) {
        accL[lane][0] = acc[0]; accL[lane][1] = acc[1];
        accL[lane][2] = acc[2]; accL[lane][3] = acc[3];
        accL[lane][4] = acc[6]; accL[lane][5] = acc[7];
    }
    __syncthreads();
    if (kw == 0) {
        const float4 bb0 = *(const float4*)(bias4 + u0 * 4);
        const float4 bb1 = *(const float4*)(bias4 + u1 * 4);
        float rr0 = 1.f / (1.f + expf(-(acc[0] + accL[lane][0] + bb0.x)));
        float rr1 = 1.f / (1.f + expf(-(acc[1] + accL[lane][1] + bb1.x)));
        float zz0 = 1.f / (1.f + expf(-(acc[2] + accL[lane][2] + bb0.y)));
        float zz1 = 1.f / (1.f + expf(-(acc[3] + accL[lane][3] + bb1.y)));
        float hn0 = acc[6] + accL[lane][4] + bb0.w;
        float hn1 = acc[7] + accL[lane][5] + bb1.w;
        float nn0 = tanhf(acc[4] + bb0.z + rr0 * hn0);
        float nn1 = tanhf(acc[5] + bb1.z + rr1 * hn1);
        houtT[(size_t)u0 * B_ + b] = (1.f - zz0) * nn0 + zz0 * hold0;
        houtT[(size_t)u1 * B_ + b] = (1.f - zz1) * nn1 + zz1 * hold1;
    }
}

// ---------------------------------------------------------------------------
// FUSED decoder step (ONE launch per step). Grid 512 x 256 thr.
// Block id = g*128 + j : group g (4 groups of 128 blocks) owns batches
// g*64..g*64+63. All syncs group-local; epochs monotonic (2st+1, 2st+2).
// Phase 1: GRU (block = 2 unit-pairs x 64 batches; x gathered via predBuf).
//          h published via sc1 (small traffic).
// Phase 2a: hw2 = h @ w2^T distributed: wave-uniform w2 row (scalar loads),
//          h read cached (first touch this launch -> fresh).
// Phase 2b: blocks j<64: attention for batch g*64+j: hw2 row (sc1) + proj
//          (cached, read-only) -> scores/softmax/argmax/loss; pred normal
//          store (visible next launch).
// ---------------------------------------------------------------------------
__global__ __launch_bounds__(256)
void dec_fused(const float* __restrict__ x,      // [B][S][F]
               const int*   __restrict__ y,      // [B][C]
               const float* __restrict__ W6,     // [256][640][6]
               const float* __restrict__ bias4,  // [512][4]
               const float* __restrict__ w2,     // [A][H]
               const float* __restrict__ v,      // [A]
               const float* __restrict__ proj,   // [B][S][A]
               const float* __restrict__ hinT,   // [H][B]
               float* __restrict__ houtT,        // [H][B]
               float* __restrict__ hw2,          // [B][A]
               int* __restrict__ predBuf,        // [B]
               float* __restrict__ nlogp, float* __restrict__ preds_out,
               int step, int* __restrict__ dflags)   // [512] packed
{
    __shared__ float accL[2][64][6];
    __shared__ float sh[512];
    __shared__ float sScore[S_], sProb[S_];

    const int tid = threadIdx.x;
    const int lane = tid & 63;
    const int wv = __builtin_amdgcn_readfirstlane(tid >> 6);   // 0..3
    const int bid = blockIdx.x;
    const int g = bid >> 7;            // group 0..3
    const int j = bid & 127;           // 0..127 within group
    const int gbase = g * 128;

    // ================ phase 1: GRU ================
    {
        const int up_local = wv & 1;
        const int kw = wv >> 1;
        const int upp = j;                     // 128 upp-blocks x 2 pairs
        const int up = upp * 2 + up_local;     // 0..255
        const int b = g * 64 + lane;
        const float* Wb = W6 + (size_t)up * 3840;
        const int u0 = up * 2, u1 = u0 + 1;

        float acc[8];
#pragma unroll
        for (int q = 0; q < 8; ++q) acc[q] = 0.f;

        float hold0 = 0.f, hold1 = 0.f;
        if (kw == 0) {
            hold0 = hinT[(size_t)u0 * B_ + b];
            hold1 = hinT[(size_t)u1 * B_ + b];
            if (step > 0) {
                int pb = predBuf[b];
                const float4* xr = (const float4*)(x + ((size_t)b * S_ + pb) * F_);
                acc_xrow(xr, Wb, acc);
            }
            acc_chunks<6>(hinT, Wb + F_ * 6, 192, b, acc);
        } else {
            acc_chunks<6>(hinT + (size_t)192 * B_, Wb + 320 * 6, 320, b, acc);
        }

        if (kw == 1) {
            accL[up_local][lane][0] = acc[0]; accL[up_local][lane][1] = acc[1];
            accL[up_local][lane][2] = acc[2]; accL[up_local][lane][3] = acc[3];
            accL[up_local][lane][4] = acc[6]; accL[up_local][lane][5] = acc[7];
        }
        __syncthreads();
        if (kw == 0)
            gru_epilogue(acc, accL[up_local], lane, bias4, u0, u1,
                         hold0, hold1, houtT, b);
        asm volatile("s_waitcnt vmcnt(0)" ::: "memory");
        __syncthreads();
        if (tid == 0) sti(&dflags[bid], 2 * step + 1);
    }

    // ================ phase 2a: hw2 slice ================
    group_wait128(dflags, gbase, tid, 2 * step + 1);
    __syncthreads();
    {
        const int a = j * 4 + wv;              // wave-uniform attention col
        const int b = g * 64 + lane;
        const float* wrow = w2 + (size_t)a * H_;
        float accw = 0.f;
        float c0[16], c1[16];
#pragma unroll
        for (int q = 0; q < 16; ++q) c0[q] = houtT[(size_t)q * B_ + b];
        for (int kc = 0; kc < H_; kc += 16) {
            if (kc + 16 < H_) {
#pragma unroll
                for (int q = 0; q < 16; ++q)
                    c1[q] = houtT[(size_t)(kc + 16 + q) * B_ + b];
            }
#pragma unroll
            for (int q = 0; q < 16; ++q)
                accw = fmaf(c0[q], wrow[kc + q], accw);
#pragma unroll
            for (int q = 0; q < 16; ++q) c0[q] = c1[q];
        }
        stf(&hw2[(size_t)b * A_ + a], accw);
        asm volatile("s_waitcnt vmcnt(0)" ::: "memory");
        __syncthreads();
        if (tid == 0) sti(&dflags[bid], 2 * step + 2);
    }

    // ================ phase 2b: attention (blocks j < 64) ================
    group_wait128(dflags, gbase, tid, 2 * step + 2);
    __syncthreads();
    if (j < 64) {
        const int bb = g * 64 + j;
        sh[tid] = ldf_sc(&hw2[(size_t)bb * A_ + tid]);
        sh[tid + 256] = ldf_sc(&hw2[(size_t)bb * A_ + tid + 256]);
        __syncthreads();

        float4 q0 = *(const float4*)&sh[lane * 8];
        float4 q1 = *(const float4*)&sh[lane * 8 + 4];
        float4 v0r = *(const float4*)(v + lane * 8);
        float4 v1r = *(const float4*)(v + lane * 8 + 4);
        const float* epb = proj + (size_t)bb * (S_ * A_);
        for (int si = 0; si < 32; ++si) {
            int s = si * 4 + wv;
            const float* row = epb + (size_t)s * A_ + lane * 8;
            float4 p0 = *(const float4*)(row);
            float4 p1 = *(const float4*)(row + 4);
            float acc = fmaxf(p0.x + q0.x, 0.f) * v0r.x
                      + fmaxf(p0.y + q0.y, 0.f) * v0r.y
                      + fmaxf(p0.z + q0.z, 0.f) * v0r.z
                      + fmaxf(p0.w + q0.w, 0.f) * v0r.w
                      + fmaxf(p1.x + q1.x, 0.f) * v1r.x
                      + fmaxf(p1.y + q1.y, 0.f) * v1r.y
                      + fmaxf(p1.z + q1.z, 0.f) * v1r.z
                      + fmaxf(p1.w + q1.w, 0.f) * v1r.w;
#pragma unroll
            for (int off = 32; off; off >>= 1) acc += __shfl_down(acc, off);
            if (lane == 0) sScore[s] = acc;
        }
        __syncthreads();

        if (tid < 64) {
            float s0v = sScore[tid], s1v = sScore[tid + 64];
            float m = fmaxf(s0v, s1v);
#pragma unroll
            for (int off = 32; off; off >>= 1) m = fmaxf(m, __shfl_xor(m, off));
            float e0 = expf(s0v - m), e1 = expf(s1v - m);
            float se = e0 + e1;
#pragma unroll
            for (int off = 32; off; off >>= 1) se += __shfl_xor(se, off);
            float p0 = e0 / se, p1 = e1 / se;
            sProb[tid] = p0; sProb[tid + 64] = p1;
            float pm = fmaxf(p0, p1);
#pragma unroll
            for (int off = 32; off; off >>= 1) pm = fmaxf(pm, __shfl_xor(pm, off));
            float t0 = expf(p0 - pm), t1 = expf(p1 - pm);
            float T = t0 + t1;
#pragma unroll
            for (int off = 32; off; off >>= 1) T += __shfl_xor(T, off);
            float bv = p0; int bi2 = tid;
            if (p1 > bv) { bv = p1; bi2 = tid + 64; }
#pragma unroll
            for (int off = 32; off; off >>= 1) {
                float ov = __shfl_xor(bv, off);
                int oi = __shfl_xor(bi2, off);
                if (ov > bv || (ov == bv && oi < bi2)) { bv = ov; bi2 = oi; }
            }
            if (tid == 0) {
                int yy = y[(size_t)bb * C_ + step];
                float py = sProb[yy];
                nlogp[(size_t)step * B_ + bb] = -(py - pm - logf(T));
                preds_out[(size_t)bb * C_ + step] = (float)bi2;
                predBuf[bb] = bi2;   // normal store; next launch sees it
            }
        }
    }
}

// ---------------------------------------------------------------------------
// proj[b][s][a] = sum_j encT[s][j][b] * w1[a][j]   (padded sB)
// ---------------------------------------------------------------------------
__global__ __launch_bounds__(256)
void proj_gemm(const float* __restrict__ encT, const float* __restrict__ w1,
               float* __restrict__ proj)
{
    __shared__ float sA[32][128];
    __shared__ float sB[32][132];
    const int tid = threadIdx.x;
    const int s = blockIdx.z;
    const int b0 = blockIdx.y * 128;
    const int a0 = blockIdx.x * 128;
    const int tx = tid & 15, ty = tid >> 4;

    float acc[8][8];
#pragma unroll
    for (int i = 0; i < 8; ++i)
#pragma unroll
        for (int jj = 0; jj < 8; ++jj) acc[i][jj] = 0.f;

    const float* Abase = encT + (size_t)s * HSLICE + b0;
    for (int kc = 0; kc < H_; kc += 32) {
#pragma unroll
        for (int p = 0; p < 16; ++p) {
            int idx = tid + p * 256;
            int kj = idx >> 7, bbb = idx & 127;
            sA[kj][bbb] = Abase[(size_t)(kc + kj) * B_ + bbb];
        }
#pragma unroll
        for (int p = 0; p < 16; ++p) {
            int idx = tid + p * 256;
            int aa = idx >> 5, kj = idx & 31;
            sB[kj][aa] = w1[(size_t)(a0 + aa) * H_ + kc + kj];
        }
        __syncthreads();
#pragma unroll
        for (int kj = 0; kj < 32; ++kj) {
            float4 af0 = *(const float4*)&sA[kj][ty * 8];
            float4 af1 = *(const float4*)&sA[kj][ty * 8 + 4];
            float4 bf0 = *(const float4*)&sB[kj][tx * 8];
            float4 bf1 = *(const float4*)&sB[kj][tx * 8 + 4];
            float am[8] = {af0.x, af0.y, af0.z, af0.w, af1.x, af1.y, af1.z, af1.w};
            float bn[8] = {bf0.x, bf0.y, bf0.z, bf0.w, bf1.x, bf1.y, bf1.z, bf1.w};
#pragma unroll
            for (int i = 0; i < 8; ++i)
#pragma unroll
                for (int jj = 0; jj < 8; ++jj)
                    acc[i][jj] = fmaf(am[i], bn[jj], acc[i][jj]);
        }
        __syncthreads();
    }
#pragma unroll
    for (int i = 0; i < 8; ++i) {
        float* dst = proj + ((size_t)(b0 + ty * 8 + i) * S_ + s) * A_ + a0 + tx * 8;
        *(float4*)(dst) = make_float4(acc[i][0], acc[i][1], acc[i][2], acc[i][3]);
        *(float4*)(dst + 4) = make_float4(acc[i][4], acc[i][5], acc[i][6], acc[i][7]);
    }
}

__global__ void final_loss(const float* __restrict__ nlogp, float* __restrict__ out)
{
    __shared__ float part[C_];
    const int i = threadIdx.x; // 128
    float s = 0.f;
    for (int b = 0; b < B_; ++b) s += nlogp[(size_t)i * B_ + b];
    part[i] = s / (float)B_;
    __syncthreads();
    if (i == 0) {
        float t = 0.f;
        for (int k = 0; k < C_; ++k) t += part[k];
        out[0] = t / (float)B_ / (float)C_;
    }
}

extern "C" void kernel_launch(void* const* d_in, const int* in_sizes, int n_in,
                              void* d_out, int out_size, void* d_ws, size_t ws_size,
                              hipStream_t stream)
{
    (void)in_sizes; (void)n_in; (void)out_size; (void)ws_size;
    const float* x    = (const float*)d_in[0];
    const int*   y    = (const int*)d_in[1];
    const float* eWih = (const float*)d_in[2];
    const float* eWhh = (const float*)d_in[3];
    const float* ebih = (const float*)d_in[4];
    const float* ebhh = (const float*)d_in[5];
    const float* dWih = (const float*)d_in[6];
    const float* dWhh = (const float*)d_in[7];
    const float* dbih = (const float*)d_in[8];
    const float* dbhh = (const float*)d_in[9];
    const float* w1   = (const float*)d_in[10];
    const float* w2   = (const float*)d_in[11];
    const float* v    = (const float*)d_in[12];
    float* out = (float*)d_out;

    float* ws = (float*)d_ws;
    // Region A [0, 16,777,216): encT (slice 127 stays live through decode).
    float* encT    = ws;
    float* encT127 = ws + (size_t)127 * HSLICE;
    // Region B [16,777,216, 33,554,432): proj. Pre-proj: xT, W6e, h0T.
    float* projB  = ws + 16777216;
    float* xT     = projB;                    // 4,194,304
    float* W6e    = projB + 4194304;          // 983,040
    float* h0T    = projB + 5177344;          // 131,072
    // Region C beyond 33,554,432:
    float* C0     = ws + 33554432;
    float* bias4e = C0;                       // 2048
    float* bias4d = C0 + 2048;                // 2048
    float* nlogp  = C0 + 4096;                // 32,768
    float* hT0    = C0 + 36864;               // 131,072
    float* hT1    = C0 + 167936;              // 131,072
    float* hw2    = C0 + 299008;              // 131,072
    float* W6d    = C0 + 430080;              // 983,040
    int*   predBuf = (int*)(C0 + 1413120);    // 256 ints
    int*   dflags  = predBuf + 256;           // 512 ints (packed)

    // ---- prep ----
    prep_all<<<dim3(3840), 256, 0, stream>>>(x, eWih, eWhh, ebih, ebhh,
                                             dbih, dbhh, xT, W6e,
                                             bias4e, bias4d, h0T, dflags);

    // ---- encoder: 128 launched steps ----
    for (int t = 0; t < S_; ++t) {
        const float* hin = (t == 0) ? h0T : encT + (size_t)(t - 1) * HSLICE;
        gru_step<<<dim3(1024), 128, 0, stream>>>(
            xT + (size_t)t * (F_ * B_), hin, W6e, bias4e,
            encT + (size_t)t * HSLICE);
    }

    // ---- proj ----
    proj_gemm<<<dim3(4, 2, 128), 256, 0, stream>>>(encT, w1, projB);

    // ---- decoder prep ----
    prep_dec<<<dim3(3840), 256, 0, stream>>>(dWih, dWhh, W6d);

    // ---- decoder: 128 fused launches ----
    float* hb[2] = { hT0, hT1 };
    for (int st = 0; st < C_; ++st) {
        const float* hin = (st == 0) ? encT127 : hb[(st & 1) ^ 1];
        float* hout = hb[st & 1];
        dec_fused<<<dim3(512), 256, 0, stream>>>(
            x, y, W6d, bias4d, w2, v, projB, hin, hout, hw2,
            predBuf, nlogp, out, st, dflags);
    }

    final_loss<<<dim3(1), 128, 0, stream>>>(nlogp, out + (size_t)B_ * C_);
}